// Round 1
// baseline (748.137 us; speedup 1.0000x reference)
//
#include <hip/hip_runtime.h>

#define HH 384
#define WW 384
#define HWSZ (HH*WW)        // 147456
#define CIN 128
#define CQ 32
#define NB 4
#define NPIX (NB*HWSZ)      // 589824

__device__ __forceinline__ float sigmoidf_(float v){ return 1.0f/(1.0f + __expf(-v)); }

// ---------------- Kernel 1: conv1x1 128 -> 32 (x = W*cen + b) ----------------
// thread = 2 pixels; weights transposed into LDS (wl[c*32+o]) for broadcast reads.
__global__ __launch_bounds__(256) void k_conv1(const float* __restrict__ cen,
    const float* __restrict__ wmat, const float* __restrict__ bvec,
    float* __restrict__ x) {
  __shared__ float wl[CIN*CQ];
  int t = threadIdx.x;
  for (int i = t; i < CIN*CQ; i += 256) {
    int c = i >> 5, o = i & 31;
    wl[i] = wmat[o*CIN + c];
  }
  __syncthreads();
  int p0  = blockIdx.x * 512 + t;          // block covers 512 aligned pixels; HWSZ%512==0 -> b uniform
  int b   = p0 / HWSZ;
  int pix = p0 - b*HWSZ;
  const float* cb = cen + (size_t)b*CIN*HWSZ + pix;
  float acc0[CQ], acc1[CQ];
  #pragma unroll
  for (int o=0;o<CQ;o++){ acc0[o]=0.f; acc1[o]=0.f; }
  for (int c=0;c<CIN;c++){
    float v0 = cb[(size_t)c*HWSZ];
    float v1 = cb[(size_t)c*HWSZ + 256];
    #pragma unroll
    for (int o=0;o<CQ;o++){
      float wv = wl[c*CQ + o];
      acc0[o] += v0*wv;
      acc1[o] += v1*wv;
    }
  }
  float* xb = x + (size_t)b*CQ*HWSZ + pix;
  #pragma unroll
  for (int o=0;o<CQ;o++){
    float bb = bvec[o];
    xb[(size_t)o*HWSZ]       = acc0[o] + bb;
    xb[(size_t)o*HWSZ + 256] = acc1[o] + bb;
  }
}

// ------------- Kernel 2: stencil + 1x1 convs -> attention scalar a -------------
__global__ __launch_bounds__(256) void k_att(const float* __restrict__ x,
    const float* __restrict__ mas, const float* __restrict__ scales,
    const float* __restrict__ base_w,
    const float* __restrict__ bn_g, const float* __restrict__ bn_b,
    const float* __restrict__ bn_m, const float* __restrict__ bn_v,
    const float* __restrict__ out_w, const float* __restrict__ out_b,
    float* __restrict__ a_out) {
  __shared__ float bwl[CQ*CQ];
  __shared__ float ows[CQ], bns[CQ], bnsh[CQ];
  int t = threadIdx.x;
  for (int i=t;i<CQ*CQ;i+=256) bwl[i] = base_w[i];
  if (t < CQ) {
    float inv = rsqrtf(bn_v[t] + 1e-3f);
    float g = bn_g[t]*inv;
    bns[t]  = g;
    bnsh[t] = bn_b[t] - bn_m[t]*g;
    ows[t]  = out_w[t];
  }
  __syncthreads();
  int p   = blockIdx.x*256 + t;
  int b   = p / HWSZ;
  int pix = p - b*HWSZ;
  int h   = pix / WW;
  int w   = pix - h*WW;

  // 17 neighborhood offsets: clamped index + 0/1 validity flag (zero padding)
  const int dh[17] = {0, -1,1,-1,1,-1,1, 0,0, -3,3,-3,3,-3,3, 0,0};
  const int dw[17] = {0, -1,1, 0,0, 1,-1,-1,1, -3,3, 0,0, 3,-3,-3,3};
  int   idx[17]; float flg[17];
  #pragma unroll
  for (int k=0;k<17;k++){
    int hh = h + dh[k], wq = w + dw[k];
    bool ok = ((unsigned)hh < (unsigned)HH) && ((unsigned)wq < (unsigned)WW);
    int hc = min(max(hh,0),HH-1), wc = min(max(wq,0),WW-1);
    idx[k] = hc*WW + wc;
    flg[k] = ok ? 1.0f : 0.0f;
  }

  const float* xb = x + (size_t)b*CQ*HWSZ;
  float feat[CQ];
  #pragma unroll
  for (int c=0;c<CQ;c++){
    const float* xc = xb + (size_t)c*HWSZ;
    float xv = xc[idx[0]];
    float n[17];
    #pragma unroll
    for (int k=1;k<17;k++) n[k] = xc[idx[k]] * flg[k];
    // shift 1: pairs (1,2)(3,4)(5,6)(7,8)
    float q0 = (xv-n[1])*(xv-n[2]);
    float q1 = (xv-n[3])*(xv-n[4]);
    float q2 = (xv-n[5])*(xv-n[6]);
    float q3 = (xv-n[7])*(xv-n[8]);
    float os0 = fminf(fminf(q0,q1),fminf(q2,q3));
    // shift 3: pairs (9,10)(11,12)(13,14)(15,16)
    float r0 = (xv-n[9])*(xv-n[10]);
    float r1 = (xv-n[11])*(xv-n[12]);
    float r2 = (xv-n[13])*(xv-n[14]);
    float r3 = (xv-n[15])*(xv-n[16]);
    float os1 = fminf(fminf(r0,r1),fminf(r2,r3));
    float v = fmaxf(os0,os1) + 0.5f*(os0+os1);
    feat[c] = fmaxf(v, 0.0f);
  }

  float att_lin = out_b[0];
  #pragma unroll
  for (int o=0;o<CQ;o++){
    float y = 0.f;
    #pragma unroll
    for (int c=0;c<CQ;c++) y += feat[c]*bwl[o*CQ+c];
    y = y*bns[o] + bnsh[o];
    att_lin += ows[o]*(y*sigmoidf_(y));   // SiLU then 1x1 to scalar
  }
  float att = sigmoidf_(att_lin);

  float s0=scales[0],s1=scales[1],s2=scales[2],s3=scales[3];
  float mx = fmaxf(fmaxf(s0,s1),fmaxf(s2,s3));
  float e0=__expf(s0-mx), e1=__expf(s1-mx), e2=__expf(s2-mx), e3=__expf(s3-mx);
  float inv = 1.0f/(e0+e1+e2+e3);
  float m = sigmoidf_(mas[p]);
  a_out[p] = (att*m)*(e0*inv) + m*(e1*inv) + att*(e2*inv) + (e3*inv);
}

// ---------------- Kernel 3: out = cen * a (broadcast over 128 ch) ----------------
__global__ __launch_bounds__(256) void k_out(const float* __restrict__ cen,
    const float* __restrict__ a, float* __restrict__ out){
  unsigned i = blockIdx.x*256u + threadIdx.x;   // float4 index
  unsigned e = i*4u;
  unsigned bc  = e / HWSZ;                      // b*128 + c
  unsigned pix = e - bc*HWSZ;
  unsigned b   = bc >> 7;
  float4 v  = ((const float4*)cen)[i];
  float4 av = ((const float4*)a)[(b*HWSZ + pix) >> 2];
  float4 r;
  r.x = v.x*av.x; r.y = v.y*av.y; r.z = v.z*av.z; r.w = v.w*av.w;
  ((float4*)out)[i] = r;
}

extern "C" void kernel_launch(void* const* d_in, const int* in_sizes, int n_in,
                              void* d_out, int out_size, void* d_ws, size_t ws_size,
                              hipStream_t stream) {
  const float* cen    = (const float*)d_in[0];
  const float* mas    = (const float*)d_in[1];
  const float* scales = (const float*)d_in[2];
  const float* in_w   = (const float*)d_in[3];
  const float* in_b   = (const float*)d_in[4];
  const float* base_w = (const float*)d_in[5];
  const float* bn_g   = (const float*)d_in[6];
  const float* bn_b   = (const float*)d_in[7];
  const float* bn_m   = (const float*)d_in[8];
  const float* bn_v   = (const float*)d_in[9];
  const float* out_w  = (const float*)d_in[10];
  const float* out_b  = (const float*)d_in[11];
  float* out = (float*)d_out;

  float* x = (float*)d_ws;                      // B*CQ*HW floats = 75.5 MB
  float* a = x + (size_t)NB*CQ*HWSZ;            // B*HW floats = 2.36 MB

  k_conv1<<<NPIX/512, 256, 0, stream>>>(cen, in_w, in_b, x);
  k_att  <<<NPIX/256, 256, 0, stream>>>(x, mas, scales, base_w,
                                        bn_g, bn_b, bn_m, bn_v, out_w, out_b, a);
  k_out  <<<(NB*CIN*HWSZ)/1024, 256, 0, stream>>>(cen, a, out);
}

// Round 2
// 725.339 us; speedup vs baseline: 1.0314x; 1.0314x over previous
//
#include <hip/hip_runtime.h>

#define HH 384
#define WW 384
#define HWSZ (HH*WW)        // 147456
#define CIN 128
#define CQ 32
#define NB 4
#define NPIX (NB*HWSZ)      // 589824

__device__ __forceinline__ float sigmoidf_(float v){ return 1.0f/(1.0f + __expf(-v)); }

// ---------------- Kernel 1: conv1x1 128 -> 32 (x = W*cen + b) ----------------
// float2 per thread (2 pixels), c unrolled x4 -> 4 loads in flight per group.
__global__ __launch_bounds__(256) void k_conv1(const float* __restrict__ cen,
    const float* __restrict__ wmat, const float* __restrict__ bvec,
    float* __restrict__ x) {
  __shared__ float wl[CIN*CQ];          // transposed [c][o]
  int t = threadIdx.x;
  for (int i = t; i < CIN*CQ; i += 256) {
    int c = i >> 5, o = i & 31;
    wl[i] = wmat[o*CIN + c];
  }
  __syncthreads();
  int p0  = blockIdx.x * 512 + t*2;     // block covers 512 aligned pixels
  int b   = p0 / HWSZ;                  // uniform per block (512 | HWSZ)
  int pix = p0 - b*HWSZ;
  const float* cb = cen + (size_t)b*CIN*HWSZ + pix;
  float2 acc[CQ];
  #pragma unroll
  for (int o=0;o<CQ;o++){ acc[o].x=0.f; acc[o].y=0.f; }
  #pragma unroll 2
  for (int c=0;c<CIN;c+=4){
    float2 v0 = *(const float2*)(cb + (size_t)(c+0)*HWSZ);
    float2 v1 = *(const float2*)(cb + (size_t)(c+1)*HWSZ);
    float2 v2 = *(const float2*)(cb + (size_t)(c+2)*HWSZ);
    float2 v3 = *(const float2*)(cb + (size_t)(c+3)*HWSZ);
    #pragma unroll
    for (int o=0;o<CQ;o++){
      float w0 = wl[(c+0)*CQ+o], w1 = wl[(c+1)*CQ+o];
      float w2 = wl[(c+2)*CQ+o], w3 = wl[(c+3)*CQ+o];
      acc[o].x = fmaf(v0.x,w0,acc[o].x); acc[o].y = fmaf(v0.y,w0,acc[o].y);
      acc[o].x = fmaf(v1.x,w1,acc[o].x); acc[o].y = fmaf(v1.y,w1,acc[o].y);
      acc[o].x = fmaf(v2.x,w2,acc[o].x); acc[o].y = fmaf(v2.y,w2,acc[o].y);
      acc[o].x = fmaf(v3.x,w3,acc[o].x); acc[o].y = fmaf(v3.y,w3,acc[o].y);
    }
  }
  float* xb = x + (size_t)b*CQ*HWSZ + pix;
  #pragma unroll
  for (int o=0;o<CQ;o++){
    float bb = bvec[o];
    float2 r; r.x = acc[o].x + bb; r.y = acc[o].y + bb;
    *(float2*)(xb + (size_t)o*HWSZ) = r;
  }
}

// ------------- Kernel 2: LDS-tiled stencil + 1x1 convs -> attention scalar -------------
#define TH 4
#define TW 64
#define LDSW 72
#define LDSN 720   // 10 rows * 72
#define GBX 6      // W/TW
#define GBY 96     // H/TH

__global__ __launch_bounds__(256) void k_att(const float* __restrict__ x,
    const float* __restrict__ mas, const float* __restrict__ scales,
    const float* __restrict__ base_w,
    const float* __restrict__ bn_g, const float* __restrict__ bn_b,
    const float* __restrict__ bn_m, const float* __restrict__ bn_v,
    const float* __restrict__ out_w, const float* __restrict__ out_b,
    float* __restrict__ a_out) {
  __shared__ float bwl[CQ*CQ];
  __shared__ float ows[CQ], bns[CQ], bnsh[CQ];
  __shared__ float tile[2][LDSN];
  int t = threadIdx.x;
  for (int i=t;i<CQ*CQ;i+=256) bwl[i] = base_w[i];
  if (t < CQ) {
    float inv = rsqrtf(bn_v[t] + 1e-3f);
    float g = bn_g[t]*inv;
    bns[t]  = g;
    bnsh[t] = bn_b[t] - bn_m[t]*g;
    ows[t]  = out_w[t];
  }

  int gid = blockIdx.x;
  int b   = gid / (GBX*GBY);
  int rem = gid - b*(GBX*GBY);
  int ty  = rem / GBX;
  int tx  = rem - ty*GBX;
  int h0  = ty*TH, w0 = tx*TW;

  // precompute staging coords (fixed across channels)
  int soff[3]; float sval[3];
  #pragma unroll
  for (int j=0;j<3;j++){
    int i = t + j*256;
    int r = i / LDSW, cc = i - r*LDSW;
    int hh = h0 - 3 + r, wq = w0 - 3 + cc;
    bool ok = (i < LDSN) && (cc < 70) &&
              ((unsigned)hh < (unsigned)HH) && ((unsigned)wq < (unsigned)WW);
    soff[j] = ok ? (hh*WW + wq) : 0;
    sval[j] = ok ? 1.0f : 0.0f;
  }

  int rr  = t >> 6, cc2 = t & 63;
  const int cbase = (3+rr)*LDSW + 3 + cc2;
  const float* xb = x + (size_t)b*CQ*HWSZ;

  float y[CQ];
  #pragma unroll
  for (int o=0;o<CQ;o++) y[o] = 0.f;

  __syncthreads();   // bwl/bns ready

  #pragma unroll 2
  for (int c=0;c<CQ;c++){
    float* buf = tile[c&1];
    const float* xc = xb + (size_t)c*HWSZ;
    #pragma unroll
    for (int j=0;j<3;j++){
      int i = t + j*256;
      if (i < LDSN) buf[i] = sval[j] * xc[soff[j]];
    }
    __syncthreads();
    const float* p = buf + cbase;
    float xv = p[0];
    float q0 = (xv-p[-LDSW-1])*(xv-p[ LDSW+1]);
    float q1 = (xv-p[-LDSW  ])*(xv-p[ LDSW  ]);
    float q2 = (xv-p[-LDSW+1])*(xv-p[ LDSW-1]);
    float q3 = (xv-p[-1     ])*(xv-p[ 1     ]);
    float os0 = fminf(fminf(q0,q1),fminf(q2,q3));
    float r0 = (xv-p[-3*LDSW-3])*(xv-p[ 3*LDSW+3]);
    float r1 = (xv-p[-3*LDSW  ])*(xv-p[ 3*LDSW  ]);
    float r2 = (xv-p[-3*LDSW+3])*(xv-p[ 3*LDSW-3]);
    float r3 = (xv-p[-3      ])*(xv-p[ 3       ]);
    float os1 = fminf(fminf(r0,r1),fminf(r2,r3));
    float v = fmaxf(os0,os1) + 0.5f*(os0+os1);
    float fc = fmaxf(v, 0.0f);
    #pragma unroll
    for (int o=0;o<CQ;o++) y[o] = fmaf(fc, bwl[o*CQ+c], y[o]);
    // next iteration stages the other buffer; the sync above orders reuse
  }

  float att_lin = out_b[0];
  #pragma unroll
  for (int o=0;o<CQ;o++){
    float yy = y[o]*bns[o] + bnsh[o];
    att_lin += ows[o]*(yy*sigmoidf_(yy));   // SiLU then 1x1 -> scalar
  }
  float att = sigmoidf_(att_lin);

  float s0=scales[0],s1=scales[1],s2=scales[2],s3=scales[3];
  float mx = fmaxf(fmaxf(s0,s1),fmaxf(s2,s3));
  float e0=__expf(s0-mx), e1=__expf(s1-mx), e2=__expf(s2-mx), e3=__expf(s3-mx);
  float inv = 1.0f/(e0+e1+e2+e3);
  int p_out = b*HWSZ + (h0+rr)*WW + (w0+cc2);
  float m = sigmoidf_(mas[p_out]);
  a_out[p_out] = (att*m)*(e0*inv) + m*(e1*inv) + att*(e2*inv) + (e3*inv);
}

// ---------------- Kernel 3: out = cen * a (broadcast over 128 ch) ----------------
__global__ __launch_bounds__(256) void k_out(const float* __restrict__ cen,
    const float* __restrict__ a, float* __restrict__ out){
  unsigned i = blockIdx.x*256u + threadIdx.x;   // float4 index
  unsigned e = i*4u;
  unsigned bc  = e / HWSZ;                      // b*128 + c
  unsigned pix = e - bc*HWSZ;
  unsigned b   = bc >> 7;
  float4 v  = ((const float4*)cen)[i];
  float4 av = ((const float4*)a)[(b*HWSZ + pix) >> 2];
  float4 r;
  r.x = v.x*av.x; r.y = v.y*av.y; r.z = v.z*av.z; r.w = v.w*av.w;
  ((float4*)out)[i] = r;
}

extern "C" void kernel_launch(void* const* d_in, const int* in_sizes, int n_in,
                              void* d_out, int out_size, void* d_ws, size_t ws_size,
                              hipStream_t stream) {
  const float* cen    = (const float*)d_in[0];
  const float* mas    = (const float*)d_in[1];
  const float* scales = (const float*)d_in[2];
  const float* in_w   = (const float*)d_in[3];
  const float* in_b   = (const float*)d_in[4];
  const float* base_w = (const float*)d_in[5];
  const float* bn_g   = (const float*)d_in[6];
  const float* bn_b   = (const float*)d_in[7];
  const float* bn_m   = (const float*)d_in[8];
  const float* bn_v   = (const float*)d_in[9];
  const float* out_w  = (const float*)d_in[10];
  const float* out_b  = (const float*)d_in[11];
  float* out = (float*)d_out;

  float* x = (float*)d_ws;                      // B*CQ*HW floats = 75.5 MB
  float* a = x + (size_t)NB*CQ*HWSZ;            // B*HW floats = 2.36 MB

  k_conv1<<<NPIX/512, 256, 0, stream>>>(cen, in_w, in_b, x);
  k_att  <<<NB*GBX*GBY, 256, 0, stream>>>(x, mas, scales, base_w,
                                          bn_g, bn_b, bn_m, bn_v, out_w, out_b, a);
  k_out  <<<(NB*CIN*HWSZ)/1024, 256, 0, stream>>>(cen, a, out);
}